// Round 12
// baseline (1149.206 us; speedup 1.0000x reference)
//
#include <hip/hip_runtime.h>
#include <math.h>
#include <stdint.h>

#define T_STEPS 100
#define B_DIM 128
#define I_DIM 1024
#define H_DIM 4096
#define O_DIM 512
#define T_CHUNK 20
#define HS_RING 21
#define HS_SLOT ((size_t)8*128*512)   // f16 per t-slot (8 m16-tiles x 128 kc x 512)
#define OV_LAG 21                     // ov step t' rides on hv step t = t'+21
#define RING_S 40                     // OG partial ring: 40 t-slots x 4 K-planes
#define TAIL_START 80                 // ov steps >= 80 handled by ov_tail
#define LEADER 127                    // hv_chunk external-publish block

typedef _Float16 f16x8 __attribute__((ext_vector_type(8)));
typedef _Float16 f16x4 __attribute__((ext_vector_type(4)));
typedef float    f32x4 __attribute__((ext_vector_type(4)));

#define AS1 __attribute__((address_space(1)))
#define AS3 __attribute__((address_space(3)))

#define ALOAD(p)    __hip_atomic_load((p), __ATOMIC_RELAXED, __HIP_MEMORY_SCOPE_AGENT)
#define ASTORE(p,v) __hip_atomic_store((p), (v), __ATOMIC_RELAXED, __HIP_MEMORY_SCOPE_AGENT)

// Block barrier with LDS-only ordering: does NOT drain vmcnt, so in-flight
// global prefetches/stores stay in flight across the barrier (the point:
// __syncthreads would serialize their latency into the per-step sync chain).
// Safe here: the cross-step protocol is value-based step-indexed flags
// (written once, no ABA), and HS/ovs writes only need kernel-end ordering.
__device__ __forceinline__ void lgkm_barrier(){
  asm volatile("s_waitcnt lgkmcnt(0)\n\ts_barrier" ::: "memory");
}

// Async global->LDS, 16B/lane. LDS dest is wave-uniform base + lane*16.
__device__ __forceinline__ void gload_lds16(const _Float16* g, _Float16* l){
  __builtin_amdgcn_global_load_lds(
      (const AS1 unsigned*)(uintptr_t)g,
      (AS3 unsigned*)(unsigned)(uintptr_t)l, 16, 0, 0);
}

// Order-preserving float->unsigned map. fmap(x)==0 only for negative NaN
// (never occurs) => 0 is the "unpublished" sentinel and acts as -inf.
__device__ __forceinline__ unsigned fmap(float f){
  unsigned u = __float_as_uint(f);
  return (u & 0x80000000u) ? ~u : (u | 0x80000000u);
}
__device__ __forceinline__ float funmap(unsigned m){
  unsigned u = (m & 0x80000000u) ? (m & 0x7FFFFFFFu) : ~m;
  return __uint_as_float(u);
}
__device__ __forceinline__ float vth_of(unsigned m){
  return 0.3f * tanhf(0.3f * funmap(m));
}

// Spin on a u64 (2 flag words) until both halves nonzero; return max of pair.
__device__ __forceinline__ unsigned poll2max(const unsigned* base, int idx){
  const unsigned long long* p = (const unsigned long long*)base + idx;
  unsigned long long v = ALOAD(p);
  while (((unsigned)v) == 0u || ((unsigned)(v >> 32)) == 0u){
    __builtin_amdgcn_s_sleep(1);
    v = ALOAD(p);
  }
  unsigned lo = (unsigned)v, hi = (unsigned)(v >> 32);
  return lo > hi ? lo : hi;
}
__device__ __forceinline__ unsigned wred_umax(unsigned v){
  #pragma unroll
  for (int o = 32; o > 0; o >>= 1){
    unsigned t = (unsigned)__shfl_down((int)v, o);
    if (t > v) v = t;
  }
  return v;
}

__global__ __launch_bounds__(256) void init_kernel(float* hv, float* ovs,
                                                   uint32_t* cnt32,
                                                   unsigned* hmaxA, unsigned* omaxA,
                                                   unsigned* hflag32, unsigned* otflag)
{
  int i = blockIdx.x * 256 + threadIdx.x;
  if (i < B_DIM*H_DIM) hv[i] = 0.f;
  if (i < B_DIM*O_DIM) ovs[i] = 0.f;
  if (i < B_DIM*O_DIM/4) cnt32[i] = 0u;
  if (i < 101*256) hflag32[i] = 0u;     // 101 steps x 128 u64 flags
  if (i < 20*128)  otflag[i] = 0u;
  if (i < 128){
    // slot0 = "max of zero state" -> fmap(0) -> vth 0 -> spike(0>0)=0.
    unsigned v = (i==0) ? 0x80000000u : 0u;
    hmaxA[i] = v; omaxA[i] = v;
  }
}

// spike_data [B][I][T] fp32 -> fragment-tiled f16 hi/lo of (x*2048), chunk of 20 t.
__global__ __launch_bounds__(256) void prep_x(const float* __restrict__ sp,
                                              _Float16* __restrict__ Ahi,
                                              _Float16* __restrict__ Alo, int t0)
{
  __shared__ float tile[32][16][10];
  const int b16 = blockIdx.x, kc = blockIdx.y, tz = blockIdx.z;
  for (int e = threadIdx.x; e < 5120; e += 256){
    int tt = e % 10, row = e / 10;
    int bb = row >> 5, ii = row & 31;
    tile[ii][bb][tt] =
      sp[((size_t)(b16*16+bb)*I_DIM + kc*32 + ii)*T_STEPS + t0 + tz*10 + tt];
  }
  __syncthreads();
  for (int u = threadIdx.x; u < 640; u += 256){
    int tl = u >> 6, l = u & 63, kg = l >> 4, r = l & 15;
    f16x8 hi, lo;
    #pragma unroll
    for (int e=0;e<8;e++){
      float x = tile[kg*8+e][r][tl] * 2048.f;
      _Float16 h = (_Float16)x;
      hi[e] = h;
      lo[e] = (_Float16)(x - (float)h);
    }
    int t_local = tz*10 + tl;
    size_t off = ((size_t)(t_local*8 + b16)*32 + kc)*512 + kg*128 + r*8;
    *(f16x8*)(Ahi + off) = hi;
    *(f16x8*)(Alo + off) = lo;
  }
}

// Wh [H][I] and Wo [O][H] fp32 -> FB-tiled f16 hi/lo of (w*256), one launch.
__global__ __launch_bounds__(256) void prep_weights(
    const float* __restrict__ Wh, const float* __restrict__ Wo,
    _Float16* __restrict__ WHhi, _Float16* __restrict__ WHlo,
    _Float16* __restrict__ WOhi, _Float16* __restrict__ WOlo)
{
  const int blk = blockIdx.x;
  if (blk < 256){
    const int n16 = blk;
    for (int u = threadIdx.x; u < 2048; u += 256){
      int kc = u >> 6, l = u & 63, kg = l >> 4, r = l & 15;
      const float* src = Wh + (size_t)(n16*16 + r)*I_DIM + kc*32 + kg*8;
      f16x8 hi, lo;
      #pragma unroll
      for (int e=0;e<8;e++){
        float x = src[e] * 256.f;
        _Float16 h = (_Float16)x;
        hi[e] = h; lo[e] = (_Float16)(x - (float)h);
      }
      size_t off = ((size_t)n16*32 + kc)*512 + kg*128 + r*8;
      *(f16x8*)(WHhi + off) = hi;
      *(f16x8*)(WHlo + off) = lo;
    }
  } else {
    const int n16 = blk - 256;
    for (int u = threadIdx.x; u < 8192; u += 256){
      int kc = u >> 6, l = u & 63, kg = l >> 4, r = l & 15;
      const float* src = Wo + (size_t)(n16*16 + r)*H_DIM + kc*32 + kg*8;
      f16x8 hi, lo;
      #pragma unroll
      for (int e=0;e<8;e++){
        float x = src[e] * 256.f;
        _Float16 h = (_Float16)x;
        hi[e] = h; lo[e] = (_Float16)(x - (float)h);
      }
      size_t off = ((size_t)(n16*128 + kc))*512 + kg*128 + r*8;
      *(f16x8*)(WOhi + off) = hi;
      *(f16x8*)(WOlo + off) = lo;
    }
  }
}

// Batched GEMM1 (chunk of 20 t): G = XT @ Wh^T via fp16x3 exact-split MFMA.
__global__ __launch_bounds__(256, 2) void gemm1_mfma(
    const _Float16* __restrict__ Ahi, const _Float16* __restrict__ Alo,
    const _Float16* __restrict__ Bhi, const _Float16* __restrict__ Blo,
    float* __restrict__ G)
{
  __shared__ __align__(16) _Float16 lds[2][4][8][512];   // 64 KB, 2 blocks/CU
  const int tid = threadIdx.x, wave = tid>>6, lane = tid&63;
  const int bn = blockIdx.x, bm = blockIdx.y;
  const int wm = wave>>1, wn = wave&1;

  const _Float16* srcbase = (wave==0)?Ahi:(wave==1)?Alo:(wave==2)?Bhi:Blo;
  const int r16b = ((wave<2) ? bm : bn)*8;
  const _Float16* gsrc = srcbase + (size_t)r16b*32*512 + lane*8;

  f32x4 acc[16];
  #pragma unroll
  for (int i=0;i<16;i++) acc[i] = (f32x4){0.f,0.f,0.f,0.f};

  #pragma unroll
  for (int q=0;q<8;q++)
    gload_lds16(gsrc + (size_t)q*32*512, &lds[0][wave][q][0]);

  for (int kc=0;kc<32;kc++){
    __syncthreads();
    if (kc < 31){
      #pragma unroll
      for (int q=0;q<8;q++)
        gload_lds16(gsrc + ((size_t)q*32 + kc+1)*512, &lds[(kc+1)&1][wave][q][0]);
    }
    const int cb = kc&1;
    f16x8 fAh[4], fAl[4], fBh[4], fBl[4];
    #pragma unroll
    for (int i=0;i<4;i++){
      fAh[i] = *(const f16x8*)&lds[cb][0][wm*4+i][lane*8];
      fAl[i] = *(const f16x8*)&lds[cb][1][wm*4+i][lane*8];
      fBh[i] = *(const f16x8*)&lds[cb][2][wn*4+i][lane*8];
      fBl[i] = *(const f16x8*)&lds[cb][3][wn*4+i][lane*8];
    }
    #pragma unroll
    for (int i=0;i<4;i++)
      #pragma unroll
      for (int j=0;j<4;j++)
        acc[i*4+j] = __builtin_amdgcn_mfma_f32_16x16x32_f16(fAh[i], fBh[j], acc[i*4+j], 0,0,0);
    #pragma unroll
    for (int i=0;i<4;i++)
      #pragma unroll
      for (int j=0;j<4;j++)
        acc[i*4+j] = __builtin_amdgcn_mfma_f32_16x16x32_f16(fAh[i], fBl[j], acc[i*4+j], 0,0,0);
    #pragma unroll
    for (int i=0;i<4;i++)
      #pragma unroll
      for (int j=0;j<4;j++)
        acc[i*4+j] = __builtin_amdgcn_mfma_f32_16x16x32_f16(fAl[i], fBh[j], acc[i*4+j], 0,0,0);
  }
  const int colw = lane&15, quad = lane>>4;
  const float sc = 1.f/(2048.f*256.f);
  float* eds = (float*)lds + wave*2048;
  __syncthreads();
  #pragma unroll
  for (int ih=0; ih<2; ih++){
    #pragma unroll
    for (int il=0; il<2; il++){
      int i = ih*2+il;
      #pragma unroll
      for (int j=0;j<4;j++)
        #pragma unroll
        for (int r=0;r<4;r++)
          eds[(il*16 + quad*4 + r)*64 + j*16 + colw] = acc[i*4+j][r]*sc;
    }
    #pragma unroll
    for (int rr8=0; rr8<8; rr8++){
      int row = rr8*4 + quad;
      float4 v = *(float4*)&eds[row*64 + colw*4];
      int m = bm*128 + wm*64 + ih*32 + row;
      int n = bn*128 + wn*64 + colw*4;
      *(float4*)&G[(size_t)m*H_DIM + n] = v;
    }
  }
}

// Per-chunk FIRST step only (t = 20c), 528 blocks. atomicMax publish is fine
// here: once per chunk, off the per-step critical path.
__global__ __launch_bounds__(256) void hv_step(
    const float* __restrict__ Gs, float* __restrict__ hv,
    _Float16* __restrict__ hs_slot,
    const unsigned* __restrict__ hmax_t, unsigned* __restrict__ hmax_n, int t,
    const float* __restrict__ OGp, float* __restrict__ ovs,
    uchar4* __restrict__ cnt8, unsigned* __restrict__ omaxA, int ovt)
{
  __shared__ float red[4];
  const int tid = threadIdx.x, lane = tid&63, wv = tid>>6;

  if (blockIdx.x < 512){
    if (t > T_STEPS) return;
    const int gid = blockIdx.x*256 + tid;     // 0..131071 (f4 index)
    const int b = gid >> 10, h0 = (gid & 1023) << 2;
    const float vth = vth_of(*hmax_t);
    float4 h = *(const float4*)(hv + (size_t)gid*4);

    if (t > 0){   // hs_{t-1} = hv_{t-1} > vth(max hv_{t-1})
      const int kc = h0>>5, kg=(h0>>3)&3, e=h0&7, r=b&15, m16l=b>>4;
      f16x4 s;
      s[0]=(h.x>vth)?(_Float16)1:(_Float16)0; s[1]=(h.y>vth)?(_Float16)1:(_Float16)0;
      s[2]=(h.z>vth)?(_Float16)1:(_Float16)0; s[3]=(h.w>vth)?(_Float16)1:(_Float16)0;
      *(f16x4*)(hs_slot + ((size_t)m16l*128 + kc)*512 + kg*128 + r*8 + e) = s;
    }
    if (t < T_STEPS){
      float4 g = *(const float4*)(Gs + (size_t)gid*4);
      float4 o;
      o.x = (h.x>vth ? 0.f : 0.5f*h.x) + g.x;
      o.y = (h.y>vth ? 0.f : 0.5f*h.y) + g.y;
      o.z = (h.z>vth ? 0.f : 0.5f*h.z) + g.z;
      o.w = (h.w>vth ? 0.f : 0.5f*h.w) + g.w;
      *(float4*)(hv + (size_t)gid*4) = o;
      float lmax = fmaxf(fmaxf(o.x,o.y),fmaxf(o.z,o.w));
      #pragma unroll
      for (int off=32; off>0; off>>=1) lmax = fmaxf(lmax, __shfl_down(lmax, off));
      if (lane==0) red[wv] = lmax;
      __syncthreads();
      if (tid==0){
        float m = fmaxf(fmaxf(red[0],red[1]),fmaxf(red[2],red[3]));
        atomicMax(hmax_n, fmap(m));
      }
    }
  } else {
    if (ovt < 0 || ovt >= TAIL_START) return;
    const int f = (int)(blockIdx.x - 512)*256 + tid;   // f4 index 0..4095
    const float vthp = vth_of(omaxA[ovt]);             // max of step ovt-1
    const int slot = ovt % RING_S;
    float lmax = -3.0e38f;
    #pragma unroll
    for (int q=0;q<4;q++){
      int o4 = f + q*4096;
      float4 v = *(const float4*)(ovs + (size_t)o4*4);
      uchar4 c = cnt8[o4];
      bool s0 = v.x > vthp, s1 = v.y > vthp, s2 = v.z > vthp, s3 = v.w > vthp;
      c.x += s0; c.y += s1; c.z += s2; c.w += s3;
      v.x = s0 ? 0.f : 0.5f*v.x;
      v.y = s1 ? 0.f : 0.5f*v.y;
      v.z = s2 ? 0.f : 0.5f*v.z;
      v.w = s3 ? 0.f : 0.5f*v.w;
      float4 g0 = *(const float4*)(OGp + ((size_t)slot*4+0)*(B_DIM*O_DIM) + (size_t)o4*4);
      float4 g1 = *(const float4*)(OGp + ((size_t)slot*4+1)*(B_DIM*O_DIM) + (size_t)o4*4);
      float4 g2 = *(const float4*)(OGp + ((size_t)slot*4+2)*(B_DIM*O_DIM) + (size_t)o4*4);
      float4 g3 = *(const float4*)(OGp + ((size_t)slot*4+3)*(B_DIM*O_DIM) + (size_t)o4*4);
      v.x += (g0.x+g1.x)+(g2.x+g3.x);
      v.y += (g0.y+g1.y)+(g2.y+g3.y);
      v.z += (g0.z+g1.z)+(g2.z+g3.z);
      v.w += (g0.w+g1.w)+(g2.w+g3.w);
      lmax = fmaxf(lmax, fmaxf(fmaxf(v.x,v.y),fmaxf(v.z,v.w)));
      *(float4*)(ovs + (size_t)o4*4) = v;
      cnt8[o4] = c;
    }
    #pragma unroll
    for (int off=32; off>0; off>>=1) lmax = fmaxf(lmax, __shfl_down(lmax, off));
    if (lane==0) red[wv] = lmax;
    __syncthreads();
    if (tid==0){
      float m = fmaxf(fmaxf(red[0],red[1]),fmaxf(red[2],red[3]));
      atomicMax(&omaxA[ovt+1], fmap(m));
    }
  }
}

// Persistent per-chunk hv chain: 128 blocks x 1024 threads, co-resident.
// Element remap: block (B0=blk>>4, H0=blk&15) owns batch rows B0*16..+15 x
// h-cols H0*256..+255. Riders spread across ALL blocks (threads 0..127).
// Per-step sync: packed u64 flag per block (h-max | o-max<<32), 1-RT all-poll.
// Per-step barriers are lgkm-only: G/OG prefetches and HS stores stay in
// flight across them (latency hides under publish+poll).
__global__ __launch_bounds__(1024) void hv_chunk(
    const float* __restrict__ Gs,          // slice for t0 (step j at Gs + j*B*H)
    float* __restrict__ hv,
    _Float16* __restrict__ HS,
    unsigned* __restrict__ hmaxA,
    const float* __restrict__ OGp, float* __restrict__ ovs,
    uchar4* __restrict__ cnt8, unsigned* __restrict__ omaxA,
    unsigned long long* __restrict__ hflag,
    int t0, int nsteps)
{
  __shared__ float red[16], redo[2];
  __shared__ unsigned sredL[2], sredH2[2];
  const int tid = threadIdx.x, lane = tid&63, wv = tid>>6;
  const int blk = blockIdx.x;                    // 0..127
  const int B0 = blk >> 4, H0 = blk & 15;
  const int b_off = tid >> 6, f4off = tid & 63;
  const int f4idx = (B0*16 + b_off)*1024 + H0*64 + f4off;
  const size_t hs_off = ((size_t)(B0*128 + H0*8 + (f4off>>3)))*512
                      + (size_t)(((f4off>>1)&3)*128 + b_off*8 + (f4off&1)*4);
  const bool ovth = tid < 128;                   // rider thread
  const int of4 = blk*128 + tid;                 // ov f4 index (rider)
  const int ovt0 = t0 - OV_LAG;
  const bool rid = (ovt0 >= 0);                  // chunk-uniform

  float4 h = *(const float4*)(hv + (size_t)f4idx*4);
  float4 vo = make_float4(0.f,0.f,0.f,0.f);
  unsigned cw = 0;
  if (rid && ovth){
    vo = *(const float4*)(ovs + (size_t)of4*4);
    uchar4 c0 = cnt8[of4];
    cw = (unsigned)c0.x | ((unsigned)c0.y<<8) | ((unsigned)c0.z<<16) | ((unsigned)c0.w<<24);
  }
  float4 g = *(const float4*)(Gs + (size_t)f4idx*4);   // step 0's G
  unsigned hm_cur = hmaxA[t0];                         // complete at kernel entry
  unsigned om_cur = rid ? omaxA[ovt0] : 0;

  // rider OG prefetch for step 0
  float4 og0,og1,og2,og3;
  og0=og1=og2=og3=make_float4(0.f,0.f,0.f,0.f);
  if (rid && ovth){
    const int sl = ovt0 % RING_S;
    const float* base = OGp + (size_t)of4*4;
    og0 = *(const float4*)(base + (size_t)(sl*4+0)*(B_DIM*O_DIM));
    og1 = *(const float4*)(base + (size_t)(sl*4+1)*(B_DIM*O_DIM));
    og2 = *(const float4*)(base + (size_t)(sl*4+2)*(B_DIM*O_DIM));
    og3 = *(const float4*)(base + (size_t)(sl*4+3)*(B_DIM*O_DIM));
  }

  for (int j = 0; j < nsteps; j++){
    const int t = t0 + j;
    const int ovt = t - OV_LAG;
    const bool last = (j == nsteps-1);

    // prefetch next step's G and rider OG early (independent of the barrier)
    float4 gn = make_float4(0.f,0.f,0.f,0.f);
    if (!last && (t+1) < T_STEPS)
      gn = *(const float4*)(Gs + (size_t)(j+1)*(B_DIM*H_DIM) + (size_t)f4idx*4);
    float4 on0,on1,on2,on3;
    on0=on1=on2=on3=make_float4(0.f,0.f,0.f,0.f);
    if (rid && ovth && !last){
      const int sln = (ovt+1) % RING_S;
      const float* base = OGp + (size_t)of4*4;
      on0 = *(const float4*)(base + (size_t)(sln*4+0)*(B_DIM*O_DIM));
      on1 = *(const float4*)(base + (size_t)(sln*4+1)*(B_DIM*O_DIM));
      on2 = *(const float4*)(base + (size_t)(sln*4+2)*(B_DIM*O_DIM));
      on3 = *(const float4*)(base + (size_t)(sln*4+3)*(B_DIM*O_DIM));
    }

    const float vth = vth_of(hm_cur);
    {  // hs_{t-1} emit (t0 >= 1 so t > 0 always here)
      f16x4 s;
      s[0]=(h.x>vth)?(_Float16)1:(_Float16)0; s[1]=(h.y>vth)?(_Float16)1:(_Float16)0;
      s[2]=(h.z>vth)?(_Float16)1:(_Float16)0; s[3]=(h.w>vth)?(_Float16)1:(_Float16)0;
      _Float16* slotp = HS + (size_t)((t-1)%HS_RING)*HS_SLOT;
      *(f16x4*)(slotp + hs_off) = s;
    }
    float lmax = -3.0e38f;
    if (t < T_STEPS){
      h.x = (h.x>vth ? 0.f : 0.5f*h.x) + g.x;
      h.y = (h.y>vth ? 0.f : 0.5f*h.y) + g.y;
      h.z = (h.z>vth ? 0.f : 0.5f*h.z) + g.z;
      h.w = (h.w>vth ? 0.f : 0.5f*h.w) + g.w;
      lmax = fmaxf(fmaxf(h.x,h.y),fmaxf(h.z,h.w));
    }

    float omax_l = -3.0e38f;
    if (rid && ovth){
      const float vthp = vth_of(om_cur);
      bool s0 = vo.x > vthp, s1 = vo.y > vthp, s2 = vo.z > vthp, s3 = vo.w > vthp;
      cw += (s0?1u:0u) | (s1?(1u<<8):0u) | (s2?(1u<<16):0u) | (s3?(1u<<24):0u);
      vo.x = s0 ? 0.f : 0.5f*vo.x;
      vo.y = s1 ? 0.f : 0.5f*vo.y;
      vo.z = s2 ? 0.f : 0.5f*vo.z;
      vo.w = s3 ? 0.f : 0.5f*vo.w;
      vo.x += (og0.x+og1.x)+(og2.x+og3.x);
      vo.y += (og0.y+og1.y)+(og2.y+og3.y);
      vo.z += (og0.z+og1.z)+(og2.z+og3.z);
      vo.w += (og0.w+og1.w)+(og2.w+og3.w);
      omax_l = fmaxf(fmaxf(vo.x,vo.y),fmaxf(vo.z,vo.w));
    }

    // block reductions (16 waves for h; waves 0,1 carry the rider o-max)
    #pragma unroll
    for (int off2=32; off2>0; off2>>=1) lmax = fmaxf(lmax, __shfl_down(lmax, off2));
    if (lane==0) red[wv] = lmax;
    if (rid && wv < 2){
      #pragma unroll
      for (int off2=32; off2>0; off2>>=1) omax_l = fmaxf(omax_l, __shfl_down(omax_l, off2));
      if (lane==0) redo[wv] = omax_l;
    }
    lgkm_barrier();

    // publish this block's packed partials: ONE 8B store, no RMW
    if (tid == 0){
      unsigned hp = 1u, op = 1u;
      if (t < T_STEPS){
        float m = red[0];
        #pragma unroll
        for (int w2=1; w2<16; w2++) m = fmaxf(m, red[w2]);
        hp = fmap(m);
      }
      if (rid) op = fmap(fmaxf(redo[0], redo[1]));
      ASTORE(&hflag[(size_t)t*128 + blk],
             (unsigned long long)hp | ((unsigned long long)op << 32));
    }

    const bool doPoll = !last || (blk == LEADER && t < T_STEPS) || (blk == 0 && rid);
    if (doPoll){
      unsigned plo = 0, phi = 0;
      if (tid < 128){
        const unsigned long long* fp = hflag + (size_t)t*128 + tid;
        unsigned long long v = ALOAD(fp);
        while (((unsigned)v) == 0u){
          __builtin_amdgcn_s_sleep(1);
          v = ALOAD(fp);
        }
        plo = (unsigned)v; phi = (unsigned)(v >> 32);
      }
      plo = wred_umax(plo);
      phi = wred_umax(phi);
      if (lane == 0 && wv < 2){ sredL[wv] = plo; sredH2[wv] = phi; }
      lgkm_barrier();
      unsigned hm2 = sredL[0] > sredL[1] ? sredL[0] : sredL[1];
      unsigned om2 = sredH2[0] > sredH2[1] ? sredH2[0] : sredH2[1];
      if (!last){
        hm_cur = hm2;
        if (rid) om_cur = om2;
      }
      if (blk == LEADER && tid == 0 && t < T_STEPS) ASTORE(&hmaxA[t+1], hm2);
      if (blk == 0 && rid && tid == 0 && ovt >= 0) ASTORE(&omaxA[ovt+1], om2);
    }
    g = gn;
    og0=on0; og1=on1; og2=on2; og3=on3;
  }

  *(float4*)(hv + (size_t)f4idx*4) = h;
  if (rid && ovth){
    *(float4*)(ovs + (size_t)of4*4) = vo;
    cnt8[of4] = make_uchar4((unsigned char)(cw & 0xffu),
                            (unsigned char)((cw>>8) & 0xffu),
                            (unsigned char)((cw>>16) & 0xffu),
                            (unsigned char)((cw>>24) & 0xffu));
  }
}

// Batched GEMM2 v3: 4-way K-split. OGp[(s%RING_S)*4 + kh] = HS[s] @ Wo^T over
// K-quarter kh. gemm1-style async-LDS double buffer.
__global__ __launch_bounds__(256, 2) void gemm2_mfma(
    const _Float16* __restrict__ HS,
    const _Float16* __restrict__ WoHi, const _Float16* __restrict__ WoLo,
    float* __restrict__ OGp, int c)
{
  __shared__ __align__(16) _Float16 lds2[2][24][512];   // 48 KB
  const int tid = threadIdx.x, wave = tid>>6, lane = tid&63;
  const int bn = blockIdx.x, bm = blockIdx.y, kh = blockIdx.z;
  const int s = c*T_CHUNK + bm, ring = s % HS_RING;
  const int wm = wave>>1, wn = wave&1;
  const int kc0 = kh*32;

  const _Float16* baseA = HS   + (size_t)ring*8*128*512 + lane*8;
  const _Float16* baseH = WoHi + (size_t)bn*8*128*512 + lane*8;
  const _Float16* baseL = WoLo + (size_t)bn*8*128*512 + lane*8;

  f32x4 acc[16];
  #pragma unroll
  for (int i=0;i<16;i++) acc[i] = (f32x4){0.f,0.f,0.f,0.f};

  #pragma unroll
  for (int i=0;i<6;i++){
    int f = wave*6 + i;
    const _Float16* g = (f<8)  ? baseA + ((size_t)f*128      + kc0)*512
                     : (f<16) ? baseH + ((size_t)(f-8)*128  + kc0)*512
                              : baseL + ((size_t)(f-16)*128 + kc0)*512;
    gload_lds16(g, &lds2[0][f][0]);
  }

  for (int k=0;k<32;k++){
    __syncthreads();              // vmcnt drain + barrier: buf[k&1] ready
    if (k < 31){
      #pragma unroll
      for (int i=0;i<6;i++){
        int f = wave*6 + i;
        const _Float16* g = (f<8)  ? baseA + ((size_t)f*128      + kc0+k+1)*512
                         : (f<16) ? baseH + ((size_t)(f-8)*128  + kc0+k+1)*512
                                  : baseL + ((size_t)(f-16)*128 + kc0+k+1)*512;
        gload_lds16(g, &lds2[(k+1)&1][f][0]);
      }
    }
    const int cb = k&1;
    f16x8 fA[4], fH[4], fL[4];
    #pragma unroll
    for (int i=0;i<4;i++){
      fA[i] = *(const f16x8*)&lds2[cb][wm*4+i][lane*8];
      fH[i] = *(const f16x8*)&lds2[cb][8+wn*4+i][lane*8];
      fL[i] = *(const f16x8*)&lds2[cb][16+wn*4+i][lane*8];
    }
    #pragma unroll
    for (int i=0;i<4;i++)
      #pragma unroll
      for (int j=0;j<4;j++)
        acc[i*4+j] = __builtin_amdgcn_mfma_f32_16x16x32_f16(fA[i], fH[j], acc[i*4+j], 0,0,0);
    #pragma unroll
    for (int i=0;i<4;i++)
      #pragma unroll
      for (int j=0;j<4;j++)
        acc[i*4+j] = __builtin_amdgcn_mfma_f32_16x16x32_f16(fA[i], fL[j], acc[i*4+j], 0,0,0);
  }
  const int colw = lane&15, quad = lane>>4;
  const float sc = 1.f/256.f;
  float* eds = (float*)lds2 + wave*2048;
  __syncthreads();
  float* OGd = OGp + ((size_t)(s % RING_S)*4 + kh)*(B_DIM*O_DIM);
  #pragma unroll
  for (int ih=0; ih<2; ih++){
    #pragma unroll
    for (int il=0; il<2; il++){
      int i = ih*2+il;
      #pragma unroll
      for (int j=0;j<4;j++)
        #pragma unroll
        for (int r=0;r<4;r++)
          eds[(il*16 + quad*4 + r)*64 + j*16 + colw] = acc[i*4+j][r]*sc;
    }
    #pragma unroll
    for (int rr8=0; rr8<8; rr8++){
      int row = rr8*4 + quad;
      float4 v = *(float4*)&eds[row*64 + colw*4];
      int m = wm*64 + ih*32 + row;
      int n = bn*128 + wn*64 + colw*4;
      *(float4*)&OGd[(size_t)m*O_DIM + n] = v;
    }
  }
}

// Tail: ov steps 80..100, 128 blocks x 128 threads (1 f4/thread).
// 1-RT redundant-reduce barrier + OG double-buffer prefetch; lgkm-only
// barriers keep the prefetch in flight across the sync chain.
__global__ __launch_bounds__(128) void ov_tail(
    const float* __restrict__ OGp, const float* __restrict__ ovs,
    const uchar4* __restrict__ cnt8, const unsigned* __restrict__ omaxA,
    unsigned* __restrict__ otflag, float* __restrict__ out)
{
  __shared__ float red[2];
  __shared__ unsigned shm;
  const int tid = threadIdx.x, lane = tid&63, wv = tid>>6;
  const int f = blockIdx.x*128 + tid;            // f4 index 0..16383
  float4 ov = *(const float4*)(ovs + (size_t)f*4);
  uchar4 c0 = cnt8[f];
  unsigned cw = (unsigned)c0.x | ((unsigned)c0.y<<8) | ((unsigned)c0.z<<16) | ((unsigned)c0.w<<24);
  unsigned om_cur = omaxA[TAIL_START];

  // prefetch OG for ovt=80
  float4 og0,og1,og2,og3;
  {
    const int sl = TAIL_START % RING_S;
    const float* base = OGp + (size_t)f*4;
    og0 = *(const float4*)(base + (size_t)(sl*4+0)*(B_DIM*O_DIM));
    og1 = *(const float4*)(base + (size_t)(sl*4+1)*(B_DIM*O_DIM));
    og2 = *(const float4*)(base + (size_t)(sl*4+2)*(B_DIM*O_DIM));
    og3 = *(const float4*)(base + (size_t)(sl*4+3)*(B_DIM*O_DIM));
  }

  for (int ovt = TAIL_START; ovt <= T_STEPS; ovt++){
    // prefetch next step's OG
    float4 n0,n1,n2,n3;
    n0=n1=n2=n3=make_float4(0.f,0.f,0.f,0.f);
    if ((ovt+1) < T_STEPS){
      const int sl = (ovt+1) % RING_S;
      const float* base = OGp + (size_t)f*4;
      n0 = *(const float4*)(base + (size_t)(sl*4+0)*(B_DIM*O_DIM));
      n1 = *(const float4*)(base + (size_t)(sl*4+1)*(B_DIM*O_DIM));
      n2 = *(const float4*)(base + (size_t)(sl*4+2)*(B_DIM*O_DIM));
      n3 = *(const float4*)(base + (size_t)(sl*4+3)*(B_DIM*O_DIM));
    }
    const float vth = vth_of(om_cur);
    bool s0 = ov.x > vth, s1 = ov.y > vth, s2 = ov.z > vth, s3 = ov.w > vth;
    cw += (s0?1u:0u) | (s1?(1u<<8):0u) | (s2?(1u<<16):0u) | (s3?(1u<<24):0u);
    ov.x = s0 ? 0.f : 0.5f*ov.x;
    ov.y = s1 ? 0.f : 0.5f*ov.y;
    ov.z = s2 ? 0.f : 0.5f*ov.z;
    ov.w = s3 ? 0.f : 0.5f*ov.w;
    if (ovt == T_STEPS) break;     // last step: spike-only
    ov.x += (og0.x+og1.x)+(og2.x+og3.x);
    ov.y += (og0.y+og1.y)+(og2.y+og3.y);
    ov.z += (og0.z+og1.z)+(og2.z+og3.z);
    ov.w += (og0.w+og1.w)+(og2.w+og3.w);
    float lmax = fmaxf(fmaxf(ov.x,ov.y),fmaxf(ov.z,ov.w));
    #pragma unroll
    for (int off=32; off>0; off>>=1) lmax = fmaxf(lmax, __shfl_down(lmax, off));
    if (lane==0) red[wv] = lmax;
    lgkm_barrier();
    if (tid==0)
      ASTORE(&otflag[(size_t)(ovt-TAIL_START)*128 + blockIdx.x],
             fmap(fmaxf(red[0], red[1])));
    if (tid < 64){
      unsigned mx = poll2max(otflag + (size_t)(ovt-TAIL_START)*128, tid);
      mx = wred_umax(mx);
      if (tid == 0) shm = mx;
    }
    lgkm_barrier();
    om_cur = shm;
    og0=n0; og1=n1; og2=n2; og3=n3;
  }
  *(float4*)(out + (size_t)f*4) = make_float4(
      (float)( cw        & 0xffu),
      (float)((cw >> 8)  & 0xffu),
      (float)((cw >> 16) & 0xffu),
      (float)((cw >> 24) & 0xffu));
}

extern "C" void kernel_launch(void* const* d_in, const int* in_sizes, int n_in,
                              void* d_out, int out_size, void* d_ws, size_t ws_size,
                              hipStream_t stream) {
  const float* spike = (const float*)d_in[0];
  const float* Wh    = (const float*)d_in[5];   // [H, I]
  const float* Wo    = (const float*)d_in[6];   // [O, H]
  float* out = (float*)d_out;

  char* ws = (char*)d_ws;
  size_t off = 0;
  _Float16* XAhi = (_Float16*)(ws+off); off += (size_t)T_CHUNK*B_DIM*I_DIM*2;
  _Float16* XAlo = (_Float16*)(ws+off); off += (size_t)T_CHUNK*B_DIM*I_DIM*2;
  _Float16* WHhi = (_Float16*)(ws+off); off += (size_t)H_DIM*I_DIM*2;
  _Float16* WHlo = (_Float16*)(ws+off); off += (size_t)H_DIM*I_DIM*2;
  _Float16* WOhi = (_Float16*)(ws+off); off += (size_t)O_DIM*H_DIM*2;
  _Float16* WOlo = (_Float16*)(ws+off); off += (size_t)O_DIM*H_DIM*2;
  float* G  = (float*)(ws+off);         off += (size_t)T_CHUNK*B_DIM*H_DIM*4;
  float* hv = (float*)(ws+off);         off += (size_t)B_DIM*H_DIM*4;
  _Float16* HS = (_Float16*)(ws+off);   off += (size_t)HS_RING*HS_SLOT*2;
  float* OGp = (float*)(ws+off);        off += (size_t)RING_S*4*B_DIM*O_DIM*4;
  float* ovs = (float*)(ws+off);        off += (size_t)B_DIM*O_DIM*4;
  uchar4* cnt8 = (uchar4*)(ws+off);     off += (size_t)B_DIM*O_DIM;
  unsigned* hmaxA = (unsigned*)(ws+off); off += 128*4;
  unsigned* omaxA = (unsigned*)(ws+off); off += 128*4;
  unsigned long long* hflag = (unsigned long long*)(ws+off); off += (size_t)101*128*8;
  unsigned* otflag = (unsigned*)(ws+off); off += (size_t)20*128*4;
  (void)ws_size; (void)in_sizes; (void)n_in; (void)out_size;

  init_kernel<<<(B_DIM*H_DIM+255)/256, 256, 0, stream>>>(
      hv, ovs, (uint32_t*)cnt8, hmaxA, omaxA, (unsigned*)hflag, otflag);
  prep_weights<<<288, 256, 0, stream>>>(Wh, Wo, WHhi, WHlo, WOhi, WOlo);

  for (int c = 0; c < T_STEPS/T_CHUNK; c++){
    prep_x<<<dim3(8,32,2), 256, 0, stream>>>(spike, XAhi, XAlo, c*T_CHUNK);
    gemm1_mfma<<<dim3(32, T_CHUNK), 256, 0, stream>>>(XAhi, XAlo, WHhi, WHlo, G);
    // first step of the chunk (t = 20c): emits hs_{20c-1}, needed by gemm2(c-1)
    {
      int t = c*T_CHUNK;
      int ring = (t == 0) ? (HS_RING-1) : ((t-1) % HS_RING);
      hv_step<<<528, 256, 0, stream>>>(
          G, hv, HS + (size_t)ring*HS_SLOT,
          hmaxA + t, hmaxA + t + 1, t,
          OGp, ovs, cnt8, omaxA, t - OV_LAG);
    }
    if (c > 0)
      gemm2_mfma<<<dim3(4, T_CHUNK, 4), 256, 0, stream>>>(HS, WOhi, WOlo, OGp, c-1);
    // persistent remainder of the chunk: t = 20c+1 .. 20c+19 (+ t=100 for c=4)
    {
      int nsteps = (c == T_STEPS/T_CHUNK - 1) ? T_CHUNK : (T_CHUNK - 1);
      hv_chunk<<<128, 1024, 0, stream>>>(
          G + (size_t)B_DIM*H_DIM, hv, HS, hmaxA,
          OGp, ovs, cnt8, omaxA, hflag,
          c*T_CHUNK + 1, nsteps);
    }
  }
  gemm2_mfma<<<dim3(4, T_CHUNK, 4), 256, 0, stream>>>(HS, WOhi, WOlo, OGp, T_STEPS/T_CHUNK - 1);
  ov_tail<<<128, 128, 0, stream>>>(OGp, ovs, cnt8, omaxA, otflag, out);
}

// Round 17
// 1139.772 us; speedup vs baseline: 1.0083x; 1.0083x over previous
//
#include <hip/hip_runtime.h>
#include <math.h>
#include <stdint.h>

#define T_STEPS 100
#define B_DIM 128
#define I_DIM 1024
#define H_DIM 4096
#define O_DIM 512
#define T_CHUNK 20
#define HS_RING 21
#define HS_SLOT ((size_t)8*128*512)   // f16 per t-slot (8 m16-tiles x 128 kc x 512)
#define OV_LAG 21                     // ov step t' rides on hv step t = t'+21
#define RING_S 40                     // OG partial ring: 40 t-slots x 4 K-planes
#define TAIL_START 80                 // ov steps >= 80 handled by ov_tail
#define LEADER 127                    // hv_chunk external-publish block

typedef _Float16 f16x8 __attribute__((ext_vector_type(8)));
typedef _Float16 f16x4 __attribute__((ext_vector_type(4)));
typedef float    f32x4 __attribute__((ext_vector_type(4)));

#define AS1 __attribute__((address_space(1)))
#define AS3 __attribute__((address_space(3)))

#define ALOAD(p)    __hip_atomic_load((p), __ATOMIC_RELAXED, __HIP_MEMORY_SCOPE_AGENT)
#define ASTORE(p,v) __hip_atomic_store((p), (v), __ATOMIC_RELAXED, __HIP_MEMORY_SCOPE_AGENT)

// Block barrier with LDS-only ordering (does NOT drain vmcnt). Measured
// neutral vs __syncthreads (r6 1142 vs r12 1149) — sync chain is RT-bound,
// not drain-bound — kept since it is not worse and avoids pointless drains.
__device__ __forceinline__ void lgkm_barrier(){
  asm volatile("s_waitcnt lgkmcnt(0)\n\ts_barrier" ::: "memory");
}

// Async global->LDS, 16B/lane. LDS dest is wave-uniform base + lane*16.
__device__ __forceinline__ void gload_lds16(const _Float16* g, _Float16* l){
  __builtin_amdgcn_global_load_lds(
      (const AS1 unsigned*)(uintptr_t)g,
      (AS3 unsigned*)(unsigned)(uintptr_t)l, 16, 0, 0);
}

// Order-preserving float->unsigned map. fmap(x)==0 only for negative NaN
// (never occurs) => 0 is the "unpublished" sentinel and acts as -inf.
__device__ __forceinline__ unsigned fmap(float f){
  unsigned u = __float_as_uint(f);
  return (u & 0x80000000u) ? ~u : (u | 0x80000000u);
}
__device__ __forceinline__ float funmap(unsigned m){
  unsigned u = (m & 0x80000000u) ? (m & 0x7FFFFFFFu) : ~m;
  return __uint_as_float(u);
}
__device__ __forceinline__ float vth_of(unsigned m){
  return 0.3f * tanhf(0.3f * funmap(m));
}

// Spin on a u64 (2 flag words) until both halves nonzero; return max of pair.
__device__ __forceinline__ unsigned poll2max(const unsigned* base, int idx){
  const unsigned long long* p = (const unsigned long long*)base + idx;
  unsigned long long v = ALOAD(p);
  while (((unsigned)v) == 0u || ((unsigned)(v >> 32)) == 0u){
    __builtin_amdgcn_s_sleep(1);
    v = ALOAD(p);
  }
  unsigned lo = (unsigned)v, hi = (unsigned)(v >> 32);
  return lo > hi ? lo : hi;
}
__device__ __forceinline__ unsigned wred_umax(unsigned v){
  #pragma unroll
  for (int o = 32; o > 0; o >>= 1){
    unsigned t = (unsigned)__shfl_down((int)v, o);
    if (t > v) v = t;
  }
  return v;
}

__global__ __launch_bounds__(256) void init_kernel(float* hv, float* ovs,
                                                   uint32_t* cnt32,
                                                   unsigned* hmaxA, unsigned* omaxA,
                                                   unsigned* hflag32, unsigned* otflag)
{
  int i = blockIdx.x * 256 + threadIdx.x;
  if (i < B_DIM*H_DIM) hv[i] = 0.f;
  if (i < B_DIM*O_DIM) ovs[i] = 0.f;
  if (i < B_DIM*O_DIM/4) cnt32[i] = 0u;
  if (i < 101*256) hflag32[i] = 0u;     // 101 steps x 128 u64 flags
  if (i < 20*128)  otflag[i] = 0u;
  if (i < 128){
    // slot0 = "max of zero state" -> fmap(0) -> vth 0 -> spike(0>0)=0.
    unsigned v = (i==0) ? 0x80000000u : 0u;
    hmaxA[i] = v; omaxA[i] = v;
  }
}

// spike_data [B][I][T] fp32 -> fragment-tiled f16 hi/lo of (x*2048), chunk of 20 t.
__global__ __launch_bounds__(256) void prep_x(const float* __restrict__ sp,
                                              _Float16* __restrict__ Ahi,
                                              _Float16* __restrict__ Alo, int t0)
{
  __shared__ float tile[32][16][10];
  const int b16 = blockIdx.x, kc = blockIdx.y, tz = blockIdx.z;
  for (int e = threadIdx.x; e < 5120; e += 256){
    int tt = e % 10, row = e / 10;
    int bb = row >> 5, ii = row & 31;
    tile[ii][bb][tt] =
      sp[((size_t)(b16*16+bb)*I_DIM + kc*32 + ii)*T_STEPS + t0 + tz*10 + tt];
  }
  __syncthreads();
  for (int u = threadIdx.x; u < 640; u += 256){
    int tl = u >> 6, l = u & 63, kg = l >> 4, r = l & 15;
    f16x8 hi, lo;
    #pragma unroll
    for (int e=0;e<8;e++){
      float x = tile[kg*8+e][r][tl] * 2048.f;
      _Float16 h = (_Float16)x;
      hi[e] = h;
      lo[e] = (_Float16)(x - (float)h);
    }
    int t_local = tz*10 + tl;
    size_t off = ((size_t)(t_local*8 + b16)*32 + kc)*512 + kg*128 + r*8;
    *(f16x8*)(Ahi + off) = hi;
    *(f16x8*)(Alo + off) = lo;
  }
}

// Wh [H][I] and Wo [O][H] fp32 -> FB-tiled f16 hi/lo of (w*256), one launch.
__global__ __launch_bounds__(256) void prep_weights(
    const float* __restrict__ Wh, const float* __restrict__ Wo,
    _Float16* __restrict__ WHhi, _Float16* __restrict__ WHlo,
    _Float16* __restrict__ WOhi, _Float16* __restrict__ WOlo)
{
  const int blk = blockIdx.x;
  if (blk < 256){
    const int n16 = blk;
    for (int u = threadIdx.x; u < 2048; u += 256){
      int kc = u >> 6, l = u & 63, kg = l >> 4, r = l & 15;
      const float* src = Wh + (size_t)(n16*16 + r)*I_DIM + kc*32 + kg*8;
      f16x8 hi, lo;
      #pragma unroll
      for (int e=0;e<8;e++){
        float x = src[e] * 256.f;
        _Float16 h = (_Float16)x;
        hi[e] = h; lo[e] = (_Float16)(x - (float)h);
      }
      size_t off = ((size_t)n16*32 + kc)*512 + kg*128 + r*8;
      *(f16x8*)(WHhi + off) = hi;
      *(f16x8*)(WHlo + off) = lo;
    }
  } else {
    const int n16 = blk - 256;
    for (int u = threadIdx.x; u < 8192; u += 256){
      int kc = u >> 6, l = u & 63, kg = l >> 4, r = l & 15;
      const float* src = Wo + (size_t)(n16*16 + r)*H_DIM + kc*32 + kg*8;
      f16x8 hi, lo;
      #pragma unroll
      for (int e=0;e<8;e++){
        float x = src[e] * 256.f;
        _Float16 h = (_Float16)x;
        hi[e] = h; lo[e] = (_Float16)(x - (float)h);
      }
      size_t off = ((size_t)(n16*128 + kc))*512 + kg*128 + r*8;
      *(f16x8*)(WOhi + off) = hi;
      *(f16x8*)(WOlo + off) = lo;
    }
  }
}

// Batched GEMM1 (chunk of 20 t): G = XT @ Wh^T via fp16x3 exact-split MFMA.
// v1 (128x128 tiles, grid 32x20) — the r12 measured-good version.
__global__ __launch_bounds__(256, 2) void gemm1_mfma(
    const _Float16* __restrict__ Ahi, const _Float16* __restrict__ Alo,
    const _Float16* __restrict__ Bhi, const _Float16* __restrict__ Blo,
    float* __restrict__ G)
{
  __shared__ __align__(16) _Float16 lds[2][4][8][512];   // 64 KB, 2 blocks/CU
  const int tid = threadIdx.x, wave = tid>>6, lane = tid&63;
  const int bn = blockIdx.x, bm = blockIdx.y;
  const int wm = wave>>1, wn = wave&1;

  const _Float16* srcbase = (wave==0)?Ahi:(wave==1)?Alo:(wave==2)?Bhi:Blo;
  const int r16b = ((wave<2) ? bm : bn)*8;
  const _Float16* gsrc = srcbase + (size_t)r16b*32*512 + lane*8;

  f32x4 acc[16];
  #pragma unroll
  for (int i=0;i<16;i++) acc[i] = (f32x4){0.f,0.f,0.f,0.f};

  #pragma unroll
  for (int q=0;q<8;q++)
    gload_lds16(gsrc + (size_t)q*32*512, &lds[0][wave][q][0]);

  for (int kc=0;kc<32;kc++){
    __syncthreads();
    if (kc < 31){
      #pragma unroll
      for (int q=0;q<8;q++)
        gload_lds16(gsrc + ((size_t)q*32 + kc+1)*512, &lds[(kc+1)&1][wave][q][0]);
    }
    const int cb = kc&1;
    f16x8 fAh[4], fAl[4], fBh[4], fBl[4];
    #pragma unroll
    for (int i=0;i<4;i++){
      fAh[i] = *(const f16x8*)&lds[cb][0][wm*4+i][lane*8];
      fAl[i] = *(const f16x8*)&lds[cb][1][wm*4+i][lane*8];
      fBh[i] = *(const f16x8*)&lds[cb][2][wn*4+i][lane*8];
      fBl[i] = *(const f16x8*)&lds[cb][3][wn*4+i][lane*8];
    }
    #pragma unroll
    for (int i=0;i<4;i++)
      #pragma unroll
      for (int j=0;j<4;j++)
        acc[i*4+j] = __builtin_amdgcn_mfma_f32_16x16x32_f16(fAh[i], fBh[j], acc[i*4+j], 0,0,0);
    #pragma unroll
    for (int i=0;i<4;i++)
      #pragma unroll
      for (int j=0;j<4;j++)
        acc[i*4+j] = __builtin_amdgcn_mfma_f32_16x16x32_f16(fAh[i], fBl[j], acc[i*4+j], 0,0,0);
    #pragma unroll
    for (int i=0;i<4;i++)
      #pragma unroll
      for (int j=0;j<4;j++)
        acc[i*4+j] = __builtin_amdgcn_mfma_f32_16x16x32_f16(fAl[i], fBh[j], acc[i*4+j], 0,0,0);
  }
  const int colw = lane&15, quad = lane>>4;
  const float sc = 1.f/(2048.f*256.f);
  float* eds = (float*)lds + wave*2048;
  __syncthreads();
  #pragma unroll
  for (int ih=0; ih<2; ih++){
    #pragma unroll
    for (int il=0; il<2; il++){
      int i = ih*2+il;
      #pragma unroll
      for (int j=0;j<4;j++)
        #pragma unroll
        for (int r=0;r<4;r++)
          eds[(il*16 + quad*4 + r)*64 + j*16 + colw] = acc[i*4+j][r]*sc;
    }
    #pragma unroll
    for (int rr8=0; rr8<8; rr8++){
      int row = rr8*4 + quad;
      float4 v = *(float4*)&eds[row*64 + colw*4];
      int m = bm*128 + wm*64 + ih*32 + row;
      int n = bn*128 + wn*64 + colw*4;
      *(float4*)&G[(size_t)m*H_DIM + n] = v;
    }
  }
}

// Per-chunk FIRST step only (t = 20c), 528 blocks. atomicMax publish is fine
// here: once per chunk, off the per-step critical path.
__global__ __launch_bounds__(256) void hv_step(
    const float* __restrict__ Gs, float* __restrict__ hv,
    _Float16* __restrict__ hs_slot,
    const unsigned* __restrict__ hmax_t, unsigned* __restrict__ hmax_n, int t,
    const float* __restrict__ OGp, float* __restrict__ ovs,
    uchar4* __restrict__ cnt8, unsigned* __restrict__ omaxA, int ovt)
{
  __shared__ float red[4];
  const int tid = threadIdx.x, lane = tid&63, wv = tid>>6;

  if (blockIdx.x < 512){
    if (t > T_STEPS) return;
    const int gid = blockIdx.x*256 + tid;     // 0..131071 (f4 index)
    const int b = gid >> 10, h0 = (gid & 1023) << 2;
    const float vth = vth_of(*hmax_t);
    float4 h = *(const float4*)(hv + (size_t)gid*4);

    if (t > 0){   // hs_{t-1} = hv_{t-1} > vth(max hv_{t-1})
      const int kc = h0>>5, kg=(h0>>3)&3, e=h0&7, r=b&15, m16l=b>>4;
      f16x4 s;
      s[0]=(h.x>vth)?(_Float16)1:(_Float16)0; s[1]=(h.y>vth)?(_Float16)1:(_Float16)0;
      s[2]=(h.z>vth)?(_Float16)1:(_Float16)0; s[3]=(h.w>vth)?(_Float16)1:(_Float16)0;
      *(f16x4*)(hs_slot + ((size_t)m16l*128 + kc)*512 + kg*128 + r*8 + e) = s;
    }
    if (t < T_STEPS){
      float4 g = *(const float4*)(Gs + (size_t)gid*4);
      float4 o;
      o.x = (h.x>vth ? 0.f : 0.5f*h.x) + g.x;
      o.y = (h.y>vth ? 0.f : 0.5f*h.y) + g.y;
      o.z = (h.z>vth ? 0.f : 0.5f*h.z) + g.z;
      o.w = (h.w>vth ? 0.f : 0.5f*h.w) + g.w;
      *(float4*)(hv + (size_t)gid*4) = o;
      float lmax = fmaxf(fmaxf(o.x,o.y),fmaxf(o.z,o.w));
      #pragma unroll
      for (int off=32; off>0; off>>=1) lmax = fmaxf(lmax, __shfl_down(lmax, off));
      if (lane==0) red[wv] = lmax;
      __syncthreads();
      if (tid==0){
        float m = fmaxf(fmaxf(red[0],red[1]),fmaxf(red[2],red[3]));
        atomicMax(hmax_n, fmap(m));
      }
    }
  } else {
    if (ovt < 0 || ovt >= TAIL_START) return;
    const int f = (int)(blockIdx.x - 512)*256 + tid;   // f4 index 0..4095
    const float vthp = vth_of(omaxA[ovt]);             // max of step ovt-1
    const int slot = ovt % RING_S;
    float lmax = -3.0e38f;
    #pragma unroll
    for (int q=0;q<4;q++){
      int o4 = f + q*4096;
      float4 v = *(const float4*)(ovs + (size_t)o4*4);
      uchar4 c = cnt8[o4];
      bool s0 = v.x > vthp, s1 = v.y > vthp, s2 = v.z > vthp, s3 = v.w > vthp;
      c.x += s0; c.y += s1; c.z += s2; c.w += s3;
      v.x = s0 ? 0.f : 0.5f*v.x;
      v.y = s1 ? 0.f : 0.5f*v.y;
      v.z = s2 ? 0.f : 0.5f*v.z;
      v.w = s3 ? 0.f : 0.5f*v.w;
      float4 g0 = *(const float4*)(OGp + ((size_t)slot*4+0)*(B_DIM*O_DIM) + (size_t)o4*4);
      float4 g1 = *(const float4*)(OGp + ((size_t)slot*4+1)*(B_DIM*O_DIM) + (size_t)o4*4);
      float4 g2 = *(const float4*)(OGp + ((size_t)slot*4+2)*(B_DIM*O_DIM) + (size_t)o4*4);
      float4 g3 = *(const float4*)(OGp + ((size_t)slot*4+3)*(B_DIM*O_DIM) + (size_t)o4*4);
      v.x += (g0.x+g1.x)+(g2.x+g3.x);
      v.y += (g0.y+g1.y)+(g2.y+g3.y);
      v.z += (g0.z+g1.z)+(g2.z+g3.z);
      v.w += (g0.w+g1.w)+(g2.w+g3.w);
      lmax = fmaxf(lmax, fmaxf(fmaxf(v.x,v.y),fmaxf(v.z,v.w)));
      *(float4*)(ovs + (size_t)o4*4) = v;
      cnt8[o4] = c;
    }
    #pragma unroll
    for (int off=32; off>0; off>>=1) lmax = fmaxf(lmax, __shfl_down(lmax, off));
    if (lane==0) red[wv] = lmax;
    __syncthreads();
    if (tid==0){
      float m = fmaxf(fmaxf(red[0],red[1]),fmaxf(red[2],red[3]));
      atomicMax(&omaxA[ovt+1], fmap(m));
    }
  }
}

// Persistent per-chunk hv chain: 128 blocks x 1024 threads, co-resident.
// Element remap: block (B0=blk>>4, H0=blk&15) owns batch rows B0*16..+15 x
// h-cols H0*256..+255. Riders spread across ALL blocks (threads 0..127).
// Per-step sync: packed u64 flag per block (h-max | o-max<<32), 1-RT all-poll.
__global__ __launch_bounds__(1024) void hv_chunk(
    const float* __restrict__ Gs,          // slice for t0 (step j at Gs + j*B*H)
    float* __restrict__ hv,
    _Float16* __restrict__ HS,
    unsigned* __restrict__ hmaxA,
    const float* __restrict__ OGp, float* __restrict__ ovs,
    uchar4* __restrict__ cnt8, unsigned* __restrict__ omaxA,
    unsigned long long* __restrict__ hflag,
    int t0, int nsteps)
{
  __shared__ float red[16], redo[2];
  __shared__ unsigned sredL[2], sredH2[2];
  const int tid = threadIdx.x, lane = tid&63, wv = tid>>6;
  const int blk = blockIdx.x;                    // 0..127
  const int B0 = blk >> 4, H0 = blk & 15;
  const int b_off = tid >> 6, f4off = tid & 63;
  const int f4idx = (B0*16 + b_off)*1024 + H0*64 + f4off;
  const size_t hs_off = ((size_t)(B0*128 + H0*8 + (f4off>>3)))*512
                      + (size_t)(((f4off>>1)&3)*128 + b_off*8 + (f4off&1)*4);
  const bool ovth = tid < 128;                   // rider thread
  const int of4 = blk*128 + tid;                 // ov f4 index (rider)
  const int ovt0 = t0 - OV_LAG;
  const bool rid = (ovt0 >= 0);                  // chunk-uniform

  float4 h = *(const float4*)(hv + (size_t)f4idx*4);
  float4 vo = make_float4(0.f,0.f,0.f,0.f);
  unsigned cw = 0;
  if (rid && ovth){
    vo = *(const float4*)(ovs + (size_t)of4*4);
    uchar4 c0 = cnt8[of4];
    cw = (unsigned)c0.x | ((unsigned)c0.y<<8) | ((unsigned)c0.z<<16) | ((unsigned)c0.w<<24);
  }
  float4 g = *(const float4*)(Gs + (size_t)f4idx*4);   // step 0's G
  unsigned hm_cur = hmaxA[t0];                         // complete at kernel entry
  unsigned om_cur = rid ? omaxA[ovt0] : 0;

  // rider OG prefetch for step 0
  float4 og0,og1,og2,og3;
  og0=og1=og2=og3=make_float4(0.f,0.f,0.f,0.f);
  if (rid && ovth){
    const int sl = ovt0 % RING_S;
    const float* base = OGp + (size_t)of4*4;
    og0 = *(const float4*)(base + (size_t)(sl*4+0)*(B_DIM*O_DIM));
    og1 = *(const float4*)(base + (size_t)(sl*4+1)*(B_DIM*O_DIM));
    og2 = *(const float4*)(base + (size_t)(sl*4+2)*(B_DIM*O_DIM));
    og3 = *(const float4*)(base + (size_t)(sl*4+3)*(B_DIM*O_DIM));
  }

  for (int j = 0; j < nsteps; j++){
    const int t = t0 + j;
    const int ovt = t - OV_LAG;
    const bool last = (j == nsteps-1);

    // prefetch next step's G and rider OG early (independent of the barrier)
    float4 gn = make_float4(0.f,0.f,0.f,0.f);
    if (!last && (t+1) < T_STEPS)
      gn = *(const float4*)(Gs + (size_t)(j+1)*(B_DIM*H_DIM) + (size_t)f4idx*4);
    float4 on0,on1,on2,on3;
    on0=on1=on2=on3=make_float4(0.f,0.f,0.f,0.f);
    if (rid && ovth && !last){
      const int sln = (ovt+1) % RING_S;
      const float* base = OGp + (size_t)of4*4;
      on0 = *(const float4*)(base + (size_t)(sln*4+0)*(B_DIM*O_DIM));
      on1 = *(const float4*)(base + (size_t)(sln*4+1)*(B_DIM*O_DIM));
      on2 = *(const float4*)(base + (size_t)(sln*4+2)*(B_DIM*O_DIM));
      on3 = *(const float4*)(base + (size_t)(sln*4+3)*(B_DIM*O_DIM));
    }

    const float vth = vth_of(hm_cur);
    {  // hs_{t-1} emit (t0 >= 1 so t > 0 always here)
      f16x4 s;
      s[0]=(h.x>vth)?(_Float16)1:(_Float16)0; s[1]=(h.y>vth)?(_Float16)1:(_Float16)0;
      s[2]=(h.z>vth)?(_Float16)1:(_Float16)0; s[3]=(h.w>vth)?(_Float16)1:(_Float16)0;
      _Float16* slotp = HS + (size_t)((t-1)%HS_RING)*HS_SLOT;
      *(f16x4*)(slotp + hs_off) = s;
    }
    float lmax = -3.0e38f;
    if (t < T_STEPS){
      h.x = (h.x>vth ? 0.f : 0.5f*h.x) + g.x;
      h.y = (h.y>vth ? 0.f : 0.5f*h.y) + g.y;
      h.z = (h.z>vth ? 0.f : 0.5f*h.z) + g.z;
      h.w = (h.w>vth ? 0.f : 0.5f*h.w) + g.w;
      lmax = fmaxf(fmaxf(h.x,h.y),fmaxf(h.z,h.w));
    }

    float omax_l = -3.0e38f;
    if (rid && ovth){
      const float vthp = vth_of(om_cur);
      bool s0 = vo.x > vthp, s1 = vo.y > vthp, s2 = vo.z > vthp, s3 = vo.w > vthp;
      cw += (s0?1u:0u) | (s1?(1u<<8):0u) | (s2?(1u<<16):0u) | (s3?(1u<<24):0u);
      vo.x = s0 ? 0.f : 0.5f*vo.x;
      vo.y = s1 ? 0.f : 0.5f*vo.y;
      vo.z = s2 ? 0.f : 0.5f*vo.z;
      vo.w = s3 ? 0.f : 0.5f*vo.w;
      vo.x += (og0.x+og1.x)+(og2.x+og3.x);
      vo.y += (og0.y+og1.y)+(og2.y+og3.y);
      vo.z += (og0.z+og1.z)+(og2.z+og3.z);
      vo.w += (og0.w+og1.w)+(og2.w+og3.w);
      omax_l = fmaxf(fmaxf(vo.x,vo.y),fmaxf(vo.z,vo.w));
    }

    // block reductions (16 waves for h; waves 0,1 carry the rider o-max)
    #pragma unroll
    for (int off2=32; off2>0; off2>>=1) lmax = fmaxf(lmax, __shfl_down(lmax, off2));
    if (lane==0) red[wv] = lmax;
    if (rid && wv < 2){
      #pragma unroll
      for (int off2=32; off2>0; off2>>=1) omax_l = fmaxf(omax_l, __shfl_down(omax_l, off2));
      if (lane==0) redo[wv] = omax_l;
    }
    lgkm_barrier();

    // publish this block's packed partials: ONE 8B store, no RMW
    if (tid == 0){
      unsigned hp = 1u, op = 1u;
      if (t < T_STEPS){
        float m = red[0];
        #pragma unroll
        for (int w2=1; w2<16; w2++) m = fmaxf(m, red[w2]);
        hp = fmap(m);
      }
      if (rid) op = fmap(fmaxf(redo[0], redo[1]));
      ASTORE(&hflag[(size_t)t*128 + blk],
             (unsigned long long)hp | ((unsigned long long)op << 32));
    }

    const bool doPoll = !last || (blk == LEADER && t < T_STEPS) || (blk == 0 && rid);
    if (doPoll){
      unsigned plo = 0, phi = 0;
      if (tid < 128){
        const unsigned long long* fp = hflag + (size_t)t*128 + tid;
        unsigned long long v = ALOAD(fp);
        while (((unsigned)v) == 0u){
          __builtin_amdgcn_s_sleep(1);
          v = ALOAD(fp);
        }
        plo = (unsigned)v; phi = (unsigned)(v >> 32);
      }
      plo = wred_umax(plo);
      phi = wred_umax(phi);
      if (lane == 0 && wv < 2){ sredL[wv] = plo; sredH2[wv] = phi; }
      lgkm_barrier();
      unsigned hm2 = sredL[0] > sredL[1] ? sredL[0] : sredL[1];
      unsigned om2 = sredH2[0] > sredH2[1] ? sredH2[0] : sredH2[1];
      if (!last){
        hm_cur = hm2;
        if (rid) om_cur = om2;
      }
      if (blk == LEADER && tid == 0 && t < T_STEPS) ASTORE(&hmaxA[t+1], hm2);
      if (blk == 0 && rid && tid == 0 && ovt >= 0) ASTORE(&omaxA[ovt+1], om2);
    }
    g = gn;
    og0=on0; og1=on1; og2=on2; og3=on3;
  }

  *(float4*)(hv + (size_t)f4idx*4) = h;
  if (rid && ovth){
    *(float4*)(ovs + (size_t)of4*4) = vo;
    cnt8[of4] = make_uchar4((unsigned char)(cw & 0xffu),
                            (unsigned char)((cw>>8) & 0xffu),
                            (unsigned char)((cw>>16) & 0xffu),
                            (unsigned char)((cw>>24) & 0xffu));
  }
}

// Batched GEMM2 v3: 4-way K-split. OGp[(s%RING_S)*4 + kh] = HS[s] @ Wo^T over
// K-quarter kh. gemm1-style async-LDS double buffer.
__global__ __launch_bounds__(256, 2) void gemm2_mfma(
    const _Float16* __restrict__ HS,
    const _Float16* __restrict__ WoHi, const _Float16* __restrict__ WoLo,
    float* __restrict__ OGp, int c)
{
  __shared__ __align__(16) _Float16 lds2[2][24][512];   // 48 KB
  const int tid = threadIdx.x, wave = tid>>6, lane = tid&63;
  const int bn = blockIdx.x, bm = blockIdx.y, kh = blockIdx.z;
  const int s = c*T_CHUNK + bm, ring = s % HS_RING;
  const int wm = wave>>1, wn = wave&1;
  const int kc0 = kh*32;

  const _Float16* baseA = HS   + (size_t)ring*8*128*512 + lane*8;
  const _Float16* baseH = WoHi + (size_t)bn*8*128*512 + lane*8;
  const _Float16* baseL = WoLo + (size_t)bn*8*128*512 + lane*8;

  f32x4 acc[16];
  #pragma unroll
  for (int i=0;i<16;i++) acc[i] = (f32x4){0.f,0.f,0.f,0.f};

  #pragma unroll
  for (int i=0;i<6;i++){
    int f = wave*6 + i;
    const _Float16* g = (f<8)  ? baseA + ((size_t)f*128      + kc0)*512
                     : (f<16) ? baseH + ((size_t)(f-8)*128  + kc0)*512
                              : baseL + ((size_t)(f-16)*128 + kc0)*512;
    gload_lds16(g, &lds2[0][f][0]);
  }

  for (int k=0;k<32;k++){
    __syncthreads();              // vmcnt drain + barrier: buf[k&1] ready
    if (k < 31){
      #pragma unroll
      for (int i=0;i<6;i++){
        int f = wave*6 + i;
        const _Float16* g = (f<8)  ? baseA + ((size_t)f*128      + kc0+k+1)*512
                         : (f<16) ? baseH + ((size_t)(f-8)*128  + kc0+k+1)*512
                                  : baseL + ((size_t)(f-16)*128 + kc0+k+1)*512;
        gload_lds16(g, &lds2[(k+1)&1][f][0]);
      }
    }
    const int cb = k&1;
    f16x8 fA[4], fH[4], fL[4];
    #pragma unroll
    for (int i=0;i<4;i++){
      fA[i] = *(const f16x8*)&lds2[cb][wm*4+i][lane*8];
      fH[i] = *(const f16x8*)&lds2[cb][8+wn*4+i][lane*8];
      fL[i] = *(const f16x8*)&lds2[cb][16+wn*4+i][lane*8];
    }
    #pragma unroll
    for (int i=0;i<4;i++)
      #pragma unroll
      for (int j=0;j<4;j++)
        acc[i*4+j] = __builtin_amdgcn_mfma_f32_16x16x32_f16(fA[i], fH[j], acc[i*4+j], 0,0,0);
    #pragma unroll
    for (int i=0;i<4;i++)
      #pragma unroll
      for (int j=0;j<4;j++)
        acc[i*4+j] = __builtin_amdgcn_mfma_f32_16x16x32_f16(fA[i], fL[j], acc[i*4+j], 0,0,0);
  }
  const int colw = lane&15, quad = lane>>4;
  const float sc = 1.f/256.f;
  float* eds = (float*)lds2 + wave*2048;
  __syncthreads();
  float* OGd = OGp + ((size_t)(s % RING_S)*4 + kh)*(B_DIM*O_DIM);
  #pragma unroll
  for (int ih=0; ih<2; ih++){
    #pragma unroll
    for (int il=0; il<2; il++){
      int i = ih*2+il;
      #pragma unroll
      for (int j=0;j<4;j++)
        #pragma unroll
        for (int r=0;r<4;r++)
          eds[(il*16 + quad*4 + r)*64 + j*16 + colw] = acc[i*4+j][r]*sc;
    }
    #pragma unroll
    for (int rr8=0; rr8<8; rr8++){
      int row = rr8*4 + quad;
      float4 v = *(float4*)&eds[row*64 + colw*4];
      int m = wm*64 + ih*32 + row;
      int n = bn*128 + wn*64 + colw*4;
      *(float4*)&OGd[(size_t)m*O_DIM + n] = v;
    }
  }
}

// Tail: ov steps 80..100, 128 blocks x 128 threads (1 f4/thread).
// 1-RT redundant-reduce barrier + OG double-buffer prefetch.
__global__ __launch_bounds__(128) void ov_tail(
    const float* __restrict__ OGp, const float* __restrict__ ovs,
    const uchar4* __restrict__ cnt8, const unsigned* __restrict__ omaxA,
    unsigned* __restrict__ otflag, float* __restrict__ out)
{
  __shared__ float red[2];
  __shared__ unsigned shm;
  const int tid = threadIdx.x, lane = tid&63, wv = tid>>6;
  const int f = blockIdx.x*128 + tid;            // f4 index 0..16383
  float4 ov = *(const float4*)(ovs + (size_t)f*4);
  uchar4 c0 = cnt8[f];
  unsigned cw = (unsigned)c0.x | ((unsigned)c0.y<<8) | ((unsigned)c0.z<<16) | ((unsigned)c0.w<<24);
  unsigned om_cur = omaxA[TAIL_START];

  // prefetch OG for ovt=80
  float4 og0,og1,og2,og3;
  {
    const int sl = TAIL_START % RING_S;
    const float* base = OGp + (size_t)f*4;
    og0 = *(const float4*)(base + (size_t)(sl*4+0)*(B_DIM*O_DIM));
    og1 = *(const float4*)(base + (size_t)(sl*4+1)*(B_DIM*O_DIM));
    og2 = *(const float4*)(base + (size_t)(sl*4+2)*(B_DIM*O_DIM));
    og3 = *(const float4*)(base + (size_t)(sl*4+3)*(B_DIM*O_DIM));
  }

  for (int ovt = TAIL_START; ovt <= T_STEPS; ovt++){
    // prefetch next step's OG
    float4 n0,n1,n2,n3;
    n0=n1=n2=n3=make_float4(0.f,0.f,0.f,0.f);
    if ((ovt+1) < T_STEPS){
      const int sl = (ovt+1) % RING_S;
      const float* base = OGp + (size_t)f*4;
      n0 = *(const float4*)(base + (size_t)(sl*4+0)*(B_DIM*O_DIM));
      n1 = *(const float4*)(base + (size_t)(sl*4+1)*(B_DIM*O_DIM));
      n2 = *(const float4*)(base + (size_t)(sl*4+2)*(B_DIM*O_DIM));
      n3 = *(const float4*)(base + (size_t)(sl*4+3)*(B_DIM*O_DIM));
    }
    const float vth = vth_of(om_cur);
    bool s0 = ov.x > vth, s1 = ov.y > vth, s2 = ov.z > vth, s3 = ov.w > vth;
    cw += (s0?1u:0u) | (s1?(1u<<8):0u) | (s2?(1u<<16):0u) | (s3?(1u<<24):0u);
    ov.x = s0 ? 0.f : 0.5f*ov.x;
    ov.y = s1 ? 0.f : 0.5f*ov.y;
    ov.z = s2 ? 0.f : 0.5f*ov.z;
    ov.w = s3 ? 0.f : 0.5f*ov.w;
    if (ovt == T_STEPS) break;     // last step: spike-only
    ov.x += (og0.x+og1.x)+(og2.x+og3.x);
    ov.y += (og0.y+og1.y)+(og2.y+og3.y);
    ov.z += (og0.z+og1.z)+(og2.z+og3.z);
    ov.w += (og0.w+og1.w)+(og2.w+og3.w);
    float lmax = fmaxf(fmaxf(ov.x,ov.y),fmaxf(ov.z,ov.w));
    #pragma unroll
    for (int off=32; off>0; off>>=1) lmax = fmaxf(lmax, __shfl_down(lmax, off));
    if (lane==0) red[wv] = lmax;
    lgkm_barrier();
    if (tid==0)
      ASTORE(&otflag[(size_t)(ovt-TAIL_START)*128 + blockIdx.x],
             fmap(fmaxf(red[0], red[1])));
    if (tid < 64){
      unsigned mx = poll2max(otflag + (size_t)(ovt-TAIL_START)*128, tid);
      mx = wred_umax(mx);
      if (tid == 0) shm = mx;
    }
    lgkm_barrier();
    om_cur = shm;
    og0=n0; og1=n1; og2=n2; og3=n3;
  }
  *(float4*)(out + (size_t)f*4) = make_float4(
      (float)( cw        & 0xffu),
      (float)((cw >> 8)  & 0xffu),
      (float)((cw >> 16) & 0xffu),
      (float)((cw >> 24) & 0xffu));
}

extern "C" void kernel_launch(void* const* d_in, const int* in_sizes, int n_in,
                              void* d_out, int out_size, void* d_ws, size_t ws_size,
                              hipStream_t stream) {
  const float* spike = (const float*)d_in[0];
  const float* Wh    = (const float*)d_in[5];   // [H, I]
  const float* Wo    = (const float*)d_in[6];   // [O, H]
  float* out = (float*)d_out;

  char* ws = (char*)d_ws;
  size_t off = 0;
  _Float16* XAhi = (_Float16*)(ws+off); off += (size_t)T_CHUNK*B_DIM*I_DIM*2;
  _Float16* XAlo = (_Float16*)(ws+off); off += (size_t)T_CHUNK*B_DIM*I_DIM*2;
  _Float16* WHhi = (_Float16*)(ws+off); off += (size_t)H_DIM*I_DIM*2;
  _Float16* WHlo = (_Float16*)(ws+off); off += (size_t)H_DIM*I_DIM*2;
  _Float16* WOhi = (_Float16*)(ws+off); off += (size_t)O_DIM*H_DIM*2;
  _Float16* WOlo = (_Float16*)(ws+off); off += (size_t)O_DIM*H_DIM*2;
  float* G  = (float*)(ws+off);         off += (size_t)T_CHUNK*B_DIM*H_DIM*4;
  float* hv = (float*)(ws+off);         off += (size_t)B_DIM*H_DIM*4;
  _Float16* HS = (_Float16*)(ws+off);   off += (size_t)HS_RING*HS_SLOT*2;
  float* OGp = (float*)(ws+off);        off += (size_t)RING_S*4*B_DIM*O_DIM*4;
  float* ovs = (float*)(ws+off);        off += (size_t)B_DIM*O_DIM*4;
  uchar4* cnt8 = (uchar4*)(ws+off);     off += (size_t)B_DIM*O_DIM;
  unsigned* hmaxA = (unsigned*)(ws+off); off += 128*4;
  unsigned* omaxA = (unsigned*)(ws+off); off += 128*4;
  unsigned long long* hflag = (unsigned long long*)(ws+off); off += (size_t)101*128*8;
  unsigned* otflag = (unsigned*)(ws+off); off += (size_t)20*128*4;
  (void)ws_size; (void)in_sizes; (void)n_in; (void)out_size;

  init_kernel<<<(B_DIM*H_DIM+255)/256, 256, 0, stream>>>(
      hv, ovs, (uint32_t*)cnt8, hmaxA, omaxA, (unsigned*)hflag, otflag);
  prep_weights<<<288, 256, 0, stream>>>(Wh, Wo, WHhi, WHlo, WOhi, WOlo);

  for (int c = 0; c < T_STEPS/T_CHUNK; c++){
    prep_x<<<dim3(8,32,2), 256, 0, stream>>>(spike, XAhi, XAlo, c*T_CHUNK);
    gemm1_mfma<<<dim3(32, T_CHUNK), 256, 0, stream>>>(XAhi, XAlo, WHhi, WHlo, G);
    // first step of the chunk (t = 20c): emits hs_{20c-1}, needed by gemm2(c-1)
    {
      int t = c*T_CHUNK;
      int ring = (t == 0) ? (HS_RING-1) : ((t-1) % HS_RING);
      hv_step<<<528, 256, 0, stream>>>(
          G, hv, HS + (size_t)ring*HS_SLOT,
          hmaxA + t, hmaxA + t + 1, t,
          OGp, ovs, cnt8, omaxA, t - OV_LAG);
    }
    if (c > 0)
      gemm2_mfma<<<dim3(4, T_CHUNK, 4), 256, 0, stream>>>(HS, WOhi, WOlo, OGp, c-1);
    // persistent remainder of the chunk: t = 20c+1 .. 20c+19 (+ t=100 for c=4)
    {
      int nsteps = (c == T_STEPS/T_CHUNK - 1) ? T_CHUNK : (T_CHUNK - 1);
      hv_chunk<<<128, 1024, 0, stream>>>(
          G + (size_t)B_DIM*H_DIM, hv, HS, hmaxA,
          OGp, ovs, cnt8, omaxA, hflag,
          c*T_CHUNK + 1, nsteps);
    }
  }
  gemm2_mfma<<<dim3(4, T_CHUNK, 4), 256, 0, stream>>>(HS, WOhi, WOlo, OGp, T_STEPS/T_CHUNK - 1);
  ov_tail<<<128, 128, 0, stream>>>(OGp, ovs, cnt8, omaxA, otflag, out);
}